// Round 10
// baseline (873.955 us; speedup 1.0000x reference)
//
#include <hip/hip_runtime.h>

#define IN_NUM 1152
#define OUT_NUM 10
#define OUT_DIM 16
#define IN_DIM 8
#define NB 256
#define KTOT 9216

// workspace float offsets
#define OFF_SPART 0
#define SZ_SPART (96 * OUT_NUM * OUT_DIM * NB)        // 3,932,160
#define OFF_BP (OFF_SPART + SZ_SPART)
#define SZ_BP (32 * IN_NUM * OUT_NUM)                 // 368,640
#define OFF_VT (OFF_BP + SZ_BP)
#define SZ_VT (NB * OUT_NUM * OUT_DIM)                // 40,960
#define OFF_WT (OFF_VT + SZ_VT)
#define SZ_WT (OUT_NUM * OUT_DIM * KTOT)              // Wt[j][d][k]
#define OFF_WT2 (OFF_WT + SZ_WT)
#define SZ_WT2 (OUT_NUM * KTOT * OUT_DIM)             // Wt2[j][k][d]
#define OFF_XT (OFF_WT2 + SZ_WT2)
#define SZ_XT (KTOT * NB)                             // xT[k][b]
#define OFF_BAR (OFF_XT + SZ_XT)                      // 2 x unsigned barrier state

#define SMEM_FLOATS 5792   // 23,168 B

// ================= phase bodies (identical math to R9, validated) =================

__device__ __forceinline__ void prep_body(float* smem, int t, int u,
                                          const float* __restrict__ x, const float* __restrict__ W,
                                          float* __restrict__ ws) {
    float* xT = ws + OFF_XT;
    float* Wt = ws + OFF_WT;
    float* Wt2 = ws + OFF_WT2;
    if (u < 576) {
        float (*lds)[68] = (float (*)[68])smem;
        int kt = u % 144, bt = u / 144;
        int k0 = kt * 64, b0 = bt * 64;
        int r = t >> 4, c4 = (t & 15) * 4;
#pragma unroll
        for (int p = 0; p < 4; ++p) {
            int bb = p * 16 + r;
            float4 v = *reinterpret_cast<const float4*>(&x[(size_t)(b0 + bb) * KTOT + k0 + c4]);
            lds[bb][c4 + 0] = v.x; lds[bb][c4 + 1] = v.y;
            lds[bb][c4 + 2] = v.z; lds[bb][c4 + 3] = v.w;
        }
        __syncthreads();
#pragma unroll
        for (int p = 0; p < 4; ++p) {
            int kk = p * 16 + r;
            float4 o;
            o.x = lds[c4 + 0][kk]; o.y = lds[c4 + 1][kk];
            o.z = lds[c4 + 2][kk]; o.w = lds[c4 + 3][kk];
            *reinterpret_cast<float4*>(&xT[(size_t)(k0 + kk) * NB + b0 + c4]) = o;
        }
    } else {
        float (*lds2)[129] = (float (*)[129])smem;
        int w = u - 576;
        int itile = w / 10, j = w - itile * 10;
        int i0 = itile * 32;
        int r0 = t >> 5, c4b = t & 31;
#pragma unroll
        for (int rr = 0; rr < 4; ++rr) {
            int rrow = rr * 8 + r0;
            float4 w4 = *reinterpret_cast<const float4*>(
                &W[(size_t)(i0 + rrow) * 1280 + j * 128 + c4b * 4]);
            lds2[rrow][c4b * 4 + 0] = w4.x; lds2[rrow][c4b * 4 + 1] = w4.y;
            lds2[rrow][c4b * 4 + 2] = w4.z; lds2[rrow][c4b * 4 + 3] = w4.w;
        }
        __syncthreads();
        int ii = t & 31, dcq = t >> 5;
#pragma unroll
        for (int rr = 0; rr < 16; ++rr) {
            int dc = rr * 8 + dcq;
            Wt[(size_t)(j * 128 + dc) * IN_NUM + i0 + ii] = lds2[ii][dc];
        }
        int d4 = t & 3, ii2 = (t >> 2) & 31, ch0 = t >> 7;
#pragma unroll
        for (int c2 = 0; c2 < 4; ++c2) {
            int c = c2 * 2 + ch0;
            float4 o;
            o.x = lds2[ii2][(d4 * 4 + 0) * 8 + c];
            o.y = lds2[ii2][(d4 * 4 + 1) * 8 + c];
            o.z = lds2[ii2][(d4 * 4 + 2) * 8 + c];
            o.w = lds2[ii2][(d4 * 4 + 3) * 8 + c];
            *reinterpret_cast<float4*>(
                &Wt2[((size_t)j * KTOT + c * IN_NUM + i0 + ii2) * OUT_DIM + d4 * 4]) = o;
        }
    }
}

__device__ __forceinline__ void p1_body(float* smem, int t, int w, int it, float* __restrict__ ws) {
    float* ldc = smem;   // 96 floats
    const float* xT = ws + OFF_XT;
    const float* Wt2 = ws + OFF_WT2;
    const float* bp = ws + OFF_BP;
    float* spart = ws + OFF_SPART;
    int g8 = w / 80, r = w - g8 * 80;
    int j = r >> 3, isp = g8 * 8 + (r & 7);
    int cch = isp / 12;
    int i0 = (isp - cch * 12) * 96;
    int k0 = isp * 96;
    if (t < 96) {
        float cv;
        if (it == 0) {
            cv = 0.1f;
        } else {
            int i = i0 + t;
            float bt_[OUT_NUM];
#pragma unroll
            for (int jp = 0; jp < OUT_NUM; ++jp) bt_[jp] = 0.f;
#pragma unroll 4
            for (int row = 0; row < 32; ++row) {
                const float2* p2 = reinterpret_cast<const float2*>(
                    &bp[(size_t)row * (IN_NUM * OUT_NUM) + i * OUT_NUM]);
#pragma unroll
                for (int q = 0; q < 5; ++q) {
                    float2 v = p2[q];
                    bt_[q * 2] += v.x; bt_[q * 2 + 1] += v.y;
                }
            }
            float m = -1e30f;
#pragma unroll
            for (int jp = 0; jp < OUT_NUM; ++jp) { bt_[jp] *= (1.f / NB); m = fmaxf(m, bt_[jp]); }
            float s = 0.f;
#pragma unroll
            for (int jp = 0; jp < OUT_NUM; ++jp) { bt_[jp] = __expf(bt_[jp] - m); s += bt_[jp]; }
            cv = bt_[j] / s;
        }
        ldc[t] = cv;
    }
    __syncthreads();
    const float* xp = xT + (size_t)k0 * NB + t;
    const float* wp = Wt2 + ((size_t)j * KTOT + k0) * OUT_DIM;   // block-uniform
    float acc[16];
#pragma unroll
    for (int d = 0; d < 16; ++d) acc[d] = 0.f;
#pragma unroll 4
    for (int kk = 0; kk < 96; ++kk) {
        float xv = xp[(size_t)kk * NB];
        float xs = xv * ldc[kk];
        const float* a = wp + kk * OUT_DIM;                      // -> s_load_dwordx16
#pragma unroll
        for (int d = 0; d < 16; ++d) acc[d] += a[d] * xs;
    }
    float* sp = spart + ((size_t)isp * OUT_NUM + j) * (OUT_DIM * NB) + t;
#pragma unroll
    for (int d = 0; d < 16; ++d) sp[d * NB] = acc[d];
}

__device__ __forceinline__ void p2_body(float* smem, int t, int wvar,
                                        const float* __restrict__ ws, float* __restrict__ dst) {
    float (*red)[32][17] = (float (*)[32][17])smem;
    float (*nrm)[9] = (float (*)[9])(smem + 4352);
    float* cf = smem + 4640;
    const float* spart = ws + OFF_SPART;
    int j = wvar >> 3, bt2 = wvar & 7;
    int ie = t >> 5, bb = t & 31;
    int b = bt2 * 32 + bb;
    float acc[16];
#pragma unroll
    for (int d = 0; d < 16; ++d) acc[d] = 0.f;
    for (int q = 0; q < 12; ++q) {
        int isp = ie * 12 + q;
        const float* sp = spart + (size_t)(isp * OUT_NUM + j) * (OUT_DIM * NB) + b;
#pragma unroll
        for (int d = 0; d < 16; ++d) acc[d] += sp[d * NB];
    }
#pragma unroll
    for (int d = 0; d < 16; ++d) red[ie][bb][d] = acc[d];
    __syncthreads();
    int bb2 = t >> 3, dp = t & 7;
    float s0 = 0.f, s1 = 0.f;
#pragma unroll
    for (int e = 0; e < 8; ++e) { s0 += red[e][bb2][dp * 2]; s1 += red[e][bb2][dp * 2 + 1]; }
    nrm[bb2][dp] = s0 * s0 + s1 * s1;
    __syncthreads();
    if (t < 32) {
        float qn = 0.f;
#pragma unroll
        for (int d = 0; d < 8; ++d) qn += nrm[t][d];
        cf[t] = qn / ((1.f + qn) * sqrtf(qn));
    }
    __syncthreads();
    float cs = cf[bb2];
    float* o = dst + (size_t)(bt2 * 32 + bb2) * (OUT_NUM * OUT_DIM) + j * OUT_DIM + dp * 2;
    o[0] = s0 * cs;
    o[1] = s1 * cs;
}

__device__ __forceinline__ void p3_body(int u, int t, int it,
                                        const float* __restrict__ x, float* __restrict__ ws) {
    const float* vt = ws + OFF_VT;
    const float* Wt = ws + OFF_WT;
    float* bp = ws + OFF_BP;
    int kt = u % 36;
    int jq = u / 36;
    int j = jq >> 2, bq = jq & 3;
    int k = kt * 256 + t;
    int c = k / IN_NUM, i = k - c * IN_NUM;
    const float* xk = x + k + (size_t)(bq * 64) * KTOT;
    const float* vjb = vt + (size_t)(bq * 64) * (OUT_NUM * OUT_DIM) + j * OUT_DIM;
    float macc[16];
#pragma unroll
    for (int d = 0; d < 16; ++d) macc[d] = 0.f;
#pragma unroll 8
    for (int b = 0; b < 64; ++b) {
        float xv = xk[(size_t)b * KTOT];
        const float* vb = vjb + (size_t)b * (OUT_NUM * OUT_DIM);   // block-uniform -> s_load
#pragma unroll
        for (int d = 0; d < 16; ++d) macc[d] += vb[d] * xv;
    }
    float bs = 0.f;
#pragma unroll
    for (int d = 0; d < 16; ++d)
        bs += macc[d] * Wt[(size_t)(j * OUT_DIM + d) * KTOT + k];
    size_t idx = (size_t)(bq * 8 + c) * (IN_NUM * OUT_NUM) + (size_t)i * OUT_NUM + j;
    float prev = (it == 0) ? 0.f : bp[idx];
    bp[idx] = prev + bs;
}

// ================= hand-rolled device-scope grid barrier =================
// Monotonic counter: barrier bn complete when cnt reaches (bn+1)*nblk. No resets -> no race.
__device__ __forceinline__ void gridbar(unsigned* cnt, unsigned* gen, int nblk, int bn, int t) {
    __syncthreads();                               // all waves' stores issued (+vmcnt drain)
    if (t == 0) {
        __threadfence();                           // release: writeback dirty L2 to LLC
        unsigned arr = atomicAdd(cnt, 1u);
        if (arr == (unsigned)((bn + 1) * nblk) - 1u) {
            atomicAdd(gen, 1u);
        } else {
            while (atomicAdd(gen, 0u) < (unsigned)(bn + 1))
                __builtin_amdgcn_s_sleep(8);
        }
    }
    __syncthreads();
    __threadfence();                               // acquire: invalidate stale L1/L2
}

// ================= persistent kernel =================
__global__ __launch_bounds__(256, 4) void k_pers(const float* __restrict__ x,
                                                 const float* __restrict__ W,
                                                 float* __restrict__ out,
                                                 float* __restrict__ ws, int nblk) {
    __shared__ float smem[SMEM_FLOATS];
    int t = threadIdx.x, bid = blockIdx.x, G = gridDim.x;
    unsigned* cnt = (unsigned*)(ws + OFF_BAR);
    unsigned* gen = cnt + 1;
    int bn = 0;

    for (int u = bid; u < 936; u += G) { __syncthreads(); prep_body(smem, t, u, x, W, ws); }
    gridbar(cnt, gen, nblk, bn++, t);
    for (int it = 0; it < 3; ++it) {
        for (int w = bid; w < 960; w += G) { __syncthreads(); p1_body(smem, t, w, it, ws); }
        gridbar(cnt, gen, nblk, bn++, t);
        float* dst = (it == 2) ? out : (ws + OFF_VT);
        for (int w = bid; w < 80; w += G) { __syncthreads(); p2_body(smem, t, w, ws, dst); }
        if (it == 2) return;
        gridbar(cnt, gen, nblk, bn++, t);
        for (int w = bid; w < 1440; w += G) p3_body(w, t, it, x, ws);
        gridbar(cnt, gen, nblk, bn++, t);
    }
}

// ================= fallback ordinary kernels (R9 structure) =================
__global__ __launch_bounds__(256) void k_prep(const float* __restrict__ x,
                                              const float* __restrict__ W,
                                              float* __restrict__ ws) {
    __shared__ float smem[SMEM_FLOATS];
    prep_body(smem, threadIdx.x, blockIdx.x, x, W, ws);
}
__global__ __launch_bounds__(256, 4) void k_p1(float* __restrict__ ws, int it) {
    __shared__ float smem[SMEM_FLOATS];
    p1_body(smem, threadIdx.x, blockIdx.x, it, ws);
}
__global__ __launch_bounds__(256, 4) void k_p2(const float* __restrict__ ws, float* __restrict__ dst) {
    __shared__ float smem[SMEM_FLOATS];
    p2_body(smem, threadIdx.x, blockIdx.x, ws, dst);
}
__global__ __launch_bounds__(256) void k_p3(const float* __restrict__ x, float* __restrict__ ws, int it) {
    p3_body(blockIdx.x, threadIdx.x, it, x, ws);
}

extern "C" void kernel_launch(void* const* d_in, const int* in_sizes, int n_in,
                              void* d_out, int out_size, void* d_ws, size_t ws_size,
                              hipStream_t stream) {
    const float* x = (const float*)d_in[0];   // [256][8][1152]
    const float* W = (const float*)d_in[1];   // [1152][10][16][8]
    float* out = (float*)d_out;               // [256][10][16][1]
    float* ws = (float*)d_ws;

    int occ = 0;
    hipError_t oe = hipOccupancyMaxActiveBlocksPerMultiprocessor(&occ, (const void*)k_pers, 256, 0);
    if (oe == hipSuccess && occ >= 1) {
        int grid = occ * 256;
        if (grid > 960) grid = 960;
        hipMemsetAsync((void*)(ws + OFF_BAR), 0, 2 * sizeof(unsigned), stream);
        k_pers<<<dim3(grid), dim3(256), 0, stream>>>(x, W, out, ws, grid);
    } else {
        k_prep<<<dim3(936), dim3(256), 0, stream>>>(x, W, ws);
        for (int it = 0; it < 3; ++it) {
            k_p1<<<dim3(960), dim3(256), 0, stream>>>(ws, it);
            k_p2<<<dim3(80), dim3(256), 0, stream>>>(ws, it == 2 ? out : (ws + OFF_VT));
            if (it < 2) k_p3<<<dim3(1440), dim3(256), 0, stream>>>(x, ws, it);
        }
    }
}

// Round 11
// 122.051 us; speedup vs baseline: 7.1606x; 7.1606x over previous
//
#include <hip/hip_runtime.h>

#define IN_NUM 1152
#define OUT_NUM 10
#define OUT_DIM 16
#define IN_DIM 8
#define NB 256
#define KTOT 9216

// workspace float offsets
#define OFF_SPART 0
#define SZ_SPART (96 * OUT_NUM * OUT_DIM * NB)        // 3,932,160
#define OFF_BP (OFF_SPART + SZ_SPART)
#define SZ_BP (32 * IN_NUM * OUT_NUM)                 // 368,640
#define OFF_VT (OFF_BP + SZ_BP)
#define SZ_VT (NB * OUT_NUM * OUT_DIM)                // 40,960
#define OFF_WT (OFF_VT + SZ_VT)
#define SZ_WT (OUT_NUM * OUT_DIM * KTOT)              // Wt[j][d][k]
#define OFF_WT2 (OFF_WT + SZ_WT)
#define SZ_WT2 (OUT_NUM * KTOT * OUT_DIM)             // Wt2[j][k][d]
#define OFF_XT (OFF_WT2 + SZ_WT2)
#define SZ_XT (KTOT * NB)                             // xT[k][b]

// ---- prep: xT[k][b] = x[b][k];  Wt[j][d*8+c][i], Wt2[j][c*1152+i][d] = W[i][j][d][c] ----
__global__ __launch_bounds__(256) void k_prep(const float* __restrict__ x,
                                              const float* __restrict__ W,
                                              float* __restrict__ xT,
                                              float* __restrict__ Wt,
                                              float* __restrict__ Wt2) {
    __shared__ float smem[64 * 68];
    int u = blockIdx.x, t = threadIdx.x;
    if (u < 576) {
        float (*lds)[68] = (float (*)[68])smem;
        int kt = u % 144, bt = u / 144;
        int k0 = kt * 64, b0 = bt * 64;
        int r = t >> 4, c4 = (t & 15) * 4;
#pragma unroll
        for (int p = 0; p < 4; ++p) {
            int bb = p * 16 + r;
            float4 v = *reinterpret_cast<const float4*>(&x[(size_t)(b0 + bb) * KTOT + k0 + c4]);
            lds[bb][c4 + 0] = v.x; lds[bb][c4 + 1] = v.y;
            lds[bb][c4 + 2] = v.z; lds[bb][c4 + 3] = v.w;
        }
        __syncthreads();
#pragma unroll
        for (int p = 0; p < 4; ++p) {
            int kk = p * 16 + r;
            float4 o;
            o.x = lds[c4 + 0][kk]; o.y = lds[c4 + 1][kk];
            o.z = lds[c4 + 2][kk]; o.w = lds[c4 + 3][kk];
            *reinterpret_cast<float4*>(&xT[(size_t)(k0 + kk) * NB + b0 + c4]) = o;
        }
    } else {
        float (*lds2)[129] = (float (*)[129])smem;
        int w = u - 576;
        int itile = w / 10, j = w - itile * 10;
        int i0 = itile * 32;
        int r0 = t >> 5, c4b = t & 31;
#pragma unroll
        for (int rr = 0; rr < 4; ++rr) {
            int rrow = rr * 8 + r0;
            float4 w4 = *reinterpret_cast<const float4*>(
                &W[(size_t)(i0 + rrow) * 1280 + j * 128 + c4b * 4]);
            lds2[rrow][c4b * 4 + 0] = w4.x; lds2[rrow][c4b * 4 + 1] = w4.y;
            lds2[rrow][c4b * 4 + 2] = w4.z; lds2[rrow][c4b * 4 + 3] = w4.w;
        }
        __syncthreads();
        int ii = t & 31, dcq = t >> 5;
#pragma unroll
        for (int rr = 0; rr < 16; ++rr) {
            int dc = rr * 8 + dcq;
            Wt[(size_t)(j * 128 + dc) * IN_NUM + i0 + ii] = lds2[ii][dc];
        }
        int d4 = t & 3, ii2 = (t >> 2) & 31, ch0 = t >> 7;
#pragma unroll
        for (int c2 = 0; c2 < 4; ++c2) {
            int c = c2 * 2 + ch0;
            float4 o;
            o.x = lds2[ii2][(d4 * 4 + 0) * 8 + c];
            o.y = lds2[ii2][(d4 * 4 + 1) * 8 + c];
            o.z = lds2[ii2][(d4 * 4 + 2) * 8 + c];
            o.w = lds2[ii2][(d4 * 4 + 3) * 8 + c];
            *reinterpret_cast<float4*>(
                &Wt2[((size_t)j * KTOT + c * IN_NUM + i0 + ii2) * OUT_DIM + d4 * 4]) = o;
        }
    }
}

// ---- p1: spart[isp][j][d][b] = sum_kk (ldc[kk]*Wt2[j][k][d]) * xT[k][b] ----
// Wt2/xT/bp are restrict-const (no alias with spart) -> A loads can scalarize (s_load_dwordx16).
__global__ __launch_bounds__(256, 4) void k_p1(const float* __restrict__ xT,
                                               const float* __restrict__ Wt2,
                                               const float* __restrict__ bp,
                                               float* __restrict__ spart, int it) {
    __shared__ float ldc[96];
    int w = blockIdx.x, t = threadIdx.x;
    int g8 = w / 80, r = w - g8 * 80;
    int j = r >> 3, isp = g8 * 8 + (r & 7);   // same-isp j-group 8 apart -> same XCD
    int cch = isp / 12;
    int i0 = (isp - cch * 12) * 96;
    int k0 = isp * 96;
    if (t < 96) {
        float cv;
        if (it == 0) {
            cv = 0.1f;
        } else {
            int i = i0 + t;
            float bt_[OUT_NUM];
#pragma unroll
            for (int jp = 0; jp < OUT_NUM; ++jp) bt_[jp] = 0.f;
#pragma unroll 4
            for (int row = 0; row < 32; ++row) {
                const float2* p2 = reinterpret_cast<const float2*>(
                    &bp[(size_t)row * (IN_NUM * OUT_NUM) + i * OUT_NUM]);
#pragma unroll
                for (int q = 0; q < 5; ++q) {
                    float2 v = p2[q];
                    bt_[q * 2] += v.x; bt_[q * 2 + 1] += v.y;
                }
            }
            float m = -1e30f;
#pragma unroll
            for (int jp = 0; jp < OUT_NUM; ++jp) { bt_[jp] *= (1.f / NB); m = fmaxf(m, bt_[jp]); }
            float s = 0.f;
#pragma unroll
            for (int jp = 0; jp < OUT_NUM; ++jp) { bt_[jp] = __expf(bt_[jp] - m); s += bt_[jp]; }
            cv = bt_[j] / s;
        }
        ldc[t] = cv;
    }
    __syncthreads();
    const float* xp = xT + (size_t)k0 * NB + t;
    const float* wp = Wt2 + ((size_t)j * KTOT + k0) * OUT_DIM;   // block-uniform, no-alias
    float acc[16];
#pragma unroll
    for (int d = 0; d < 16; ++d) acc[d] = 0.f;
#pragma unroll 4
    for (int kk = 0; kk < 96; ++kk) {
        float xv = xp[(size_t)kk * NB];
        float xs = xv * ldc[kk];
        const float* a = wp + kk * OUT_DIM;                      // -> s_load_dwordx16
#pragma unroll
        for (int d = 0; d < 16; ++d) acc[d] += a[d] * xs;
    }
    float* sp = spart + ((size_t)isp * OUT_NUM + j) * (OUT_DIM * NB) + t;
#pragma unroll
    for (int d = 0; d < 16; ++d) sp[d * NB] = acc[d];
}

// ---- p2: reduce spart over isp, squash, write dst[b][j][d] ----
__global__ __launch_bounds__(256, 4) void k_p2(const float* __restrict__ spart,
                                               float* __restrict__ dst) {
    __shared__ float smem[4672];
    float (*red)[32][17] = (float (*)[32][17])smem;
    float (*nrm)[9] = (float (*)[9])(smem + 4352);
    float* cf = smem + 4640;
    int wvar = blockIdx.x, t = threadIdx.x;
    int j = wvar >> 3, bt2 = wvar & 7;
    int ie = t >> 5, bb = t & 31;
    int b = bt2 * 32 + bb;
    float acc[16];
#pragma unroll
    for (int d = 0; d < 16; ++d) acc[d] = 0.f;
    for (int q = 0; q < 12; ++q) {
        int isp = ie * 12 + q;
        const float* sp = spart + (size_t)(isp * OUT_NUM + j) * (OUT_DIM * NB) + b;
#pragma unroll
        for (int d = 0; d < 16; ++d) acc[d] += sp[d * NB];
    }
#pragma unroll
    for (int d = 0; d < 16; ++d) red[ie][bb][d] = acc[d];
    __syncthreads();
    int bb2 = t >> 3, dp = t & 7;
    float s0 = 0.f, s1 = 0.f;
#pragma unroll
    for (int e = 0; e < 8; ++e) { s0 += red[e][bb2][dp * 2]; s1 += red[e][bb2][dp * 2 + 1]; }
    nrm[bb2][dp] = s0 * s0 + s1 * s1;
    __syncthreads();
    if (t < 32) {
        float qn = 0.f;
#pragma unroll
        for (int d = 0; d < 8; ++d) qn += nrm[t][d];
        cf[t] = qn / ((1.f + qn) * sqrtf(qn));
    }
    __syncthreads();
    float cs = cf[bb2];
    float* o = dst + (size_t)(bt2 * 32 + bb2) * (OUT_NUM * OUT_DIM) + j * OUT_DIM + dp * 2;
    o[0] = s0 * cs;
    o[1] = s1 * cs;
}

// ---- p3: bp[bq*8+c][i][j] = prev + sum_d Wt[j][d][k] * sum_{b in quarter} vt[b][j][d]*x[b][k] ----
// vt/Wt/x restrict-const (no alias with bp) -> vt loads scalarize (s_load).
__global__ __launch_bounds__(256) void k_p3(const float* __restrict__ x,
                                            const float* __restrict__ vt,
                                            const float* __restrict__ Wt,
                                            float* __restrict__ bp, int it) {
    int u = blockIdx.x, t = threadIdx.x;
    int kt = u % 36;
    int jq = u / 36;
    int j = jq >> 2, bq = jq & 3;
    int k = kt * 256 + t;
    int c = k / IN_NUM, i = k - c * IN_NUM;
    const float* xk = x + k + (size_t)(bq * 64) * KTOT;
    const float* vjb = vt + (size_t)(bq * 64) * (OUT_NUM * OUT_DIM) + j * OUT_DIM;
    float macc[16];
#pragma unroll
    for (int d = 0; d < 16; ++d) macc[d] = 0.f;
#pragma unroll 8
    for (int b = 0; b < 64; ++b) {
        float xv = xk[(size_t)b * KTOT];
        const float* vb = vjb + (size_t)b * (OUT_NUM * OUT_DIM);   // block-uniform -> s_load
#pragma unroll
        for (int d = 0; d < 16; ++d) macc[d] += vb[d] * xv;
    }
    float bs = 0.f;
#pragma unroll
    for (int d = 0; d < 16; ++d)
        bs += macc[d] * Wt[(size_t)(j * OUT_DIM + d) * KTOT + k];
    size_t idx = (size_t)(bq * 8 + c) * (IN_NUM * OUT_NUM) + (size_t)i * OUT_NUM + j;
    float prev = (it == 0) ? 0.f : bp[idx];
    bp[idx] = prev + bs;
}

extern "C" void kernel_launch(void* const* d_in, const int* in_sizes, int n_in,
                              void* d_out, int out_size, void* d_ws, size_t ws_size,
                              hipStream_t stream) {
    const float* x = (const float*)d_in[0];   // [256][8][1152]
    const float* W = (const float*)d_in[1];   // [1152][10][16][8]
    float* out = (float*)d_out;               // [256][10][16][1]
    float* ws = (float*)d_ws;

    float* spart = ws + OFF_SPART;
    float* bp    = ws + OFF_BP;
    float* vt    = ws + OFF_VT;
    float* Wt    = ws + OFF_WT;
    float* Wt2   = ws + OFF_WT2;
    float* xT    = ws + OFF_XT;

    k_prep<<<dim3(936), dim3(256), 0, stream>>>(x, W, xT, Wt, Wt2);
    for (int it = 0; it < 3; ++it) {
        k_p1<<<dim3(960), dim3(256), 0, stream>>>(xT, Wt2, bp, spart, it);
        k_p2<<<dim3(80), dim3(256), 0, stream>>>(spart, it == 2 ? out : vt);
        if (it < 2) k_p3<<<dim3(1440), dim3(256), 0, stream>>>(x, vt, Wt, bp, it);
    }
}